// Round 12
// baseline (118.805 us; speedup 1.0000x reference)
//
#include <hip/hip_runtime.h>

#define B_ 4
#define T_ 1024
#define C_ 1024
#define H_ 16
#define HD_ 64

typedef short bf16x8 __attribute__((ext_vector_type(8)));
typedef float f32x4 __attribute__((ext_vector_type(4)));

__device__ __forceinline__ ushort f2bf(float f) {
    union { float f; unsigned u; } v; v.f = f;
    unsigned u = v.u;
    unsigned r = (u + 0x7fffu + ((u >> 16) & 1u)) >> 16;
    return (ushort)r;
}

__device__ __forceinline__ f32x4 mfma16(bf16x8 a, bf16x8 b, f32x4 c) {
    return __builtin_amdgcn_mfma_f32_16x16x32_bf16(a, b, c, 0, 0, 0);
}

// [rows][64] ushort tile, swizzle byte ^= (row&7)<<4 (K/B tiles).
__device__ __forceinline__ bf16x8 lds_frag(const ushort* base, int row, int byteoff) {
    int addr = (row * 128 + byteoff) ^ ((row & 7) << 4);
    uint4 u = *(const uint4*)((const char*)base + addr);
    return __builtin_bit_cast(bf16x8, u);
}

// V^T tile: byte ^= (((d&7)^(d>>3))&7)<<4.
__device__ __forceinline__ bf16x8 lds_frag_v(const ushort* base, int d, int byteoff) {
    int addr = (d * 128 + byteoff) ^ ((((d & 7) ^ (d >> 3)) & 7) << 4);
    uint4 u = *(const uint4*)((const char*)base + addr);
    return __builtin_bit_cast(bf16x8, u);
}

// P tile (16 rows): swizzle ((row>>2)&3)<<5.
__device__ __forceinline__ bf16x8 lds_frag_p(const ushort* base, int row, int byteoff) {
    int addr = (row * 128 + byteoff) ^ (((row >> 2) & 3) << 5);
    uint4 u = *(const uint4*)((const char*)base + addr);
    return __builtin_bit_cast(bf16x8, u);
}

// One fused cast kernel for all three fp32->bf16 conversions.
__global__ void cast_all(const float* __restrict__ x, const float* __restrict__ wqkv,
                         const float* __restrict__ wout,
                         ushort* __restrict__ xb, ushort* __restrict__ wqkvb,
                         ushort* __restrict__ woutb) {
    int i = (blockIdx.x * 256 + threadIdx.x) * 4;
    const float* src; ushort* dst; int off;
    if (i < 4194304)      { src = x;    dst = xb;    off = i; }
    else if (i < 7340032) { src = wqkv; dst = wqkvb; off = i - 4194304; }
    else                  { src = wout; dst = woutb; off = i - 7340032; }
    float4 v = *(const float4*)(src + off);
    ushort4 o = make_ushort4(f2bf(v.x), f2bf(v.y), f2bf(v.z), f2bf(v.w));
    *(ushort4*)(dst + off) = o;
}

// ---------------------------------------------------------------------------
// GEMM core: block 128(M) x 64(N), BK=64, 4 waves each 32x64.
// r11 was LDS-PORT-BOUND (48 rd + 24 wr b128/iter ~= 864cy -> 35us/CU floor).
// THIS ROUND: A bypasses LDS entirely — each wave loads its A fragments
// straight from global (L2-hot: all 1536 blocks resident, 48 share a slab;
// one wave-instr = 16 rows x one 64B line). A-frags are register-double-
// buffered (x../y.. named regs, loaded at compute start for kt+1 -> drained
// at the next barrier after a full compute phase). B keeps named-reg staging.
// LDS traffic/iter drops 72KB -> 24KB (8 wr + 32 rd instrs ~= 480cy).
// ---------------------------------------------------------------------------

// ---------------------------------------------------------------------------
// GEMM1: qkv = x @ W_qkv^T, fused RoPE + norms + kappa-prescale.
// Grid (32 m, 48 n) x-major. N-tile = 64 = one (sector, head).
// ---------------------------------------------------------------------------
__global__ __launch_bounds__(256) void gemm_qkv(
    const ushort* __restrict__ Xb, const ushort* __restrict__ Wb,
    const float* __restrict__ hyp,
    ushort* __restrict__ Qo, ushort* __restrict__ Ko, ushort* __restrict__ Vo,
    float* __restrict__ q0g, float* __restrict__ k0g)
{
    __shared__ ushort Bs[64 * 64];
    const int tid = threadIdx.x, lane = tid & 63, wv = tid >> 6;
    const int m0 = blockIdx.x * 128, n0 = blockIdx.y * 64;
    const ushort* Bsrc = Wb + (size_t)n0 * C_;
    const ushort* Arow = Xb + (size_t)(m0 + wv * 32 + (lane & 15)) * C_ + ((lane >> 4) << 3);

    const int srow = tid >> 3, soff = (tid & 7) * 8;
    const int swz = (srow & 7) << 4;
    uint4 b0, b1;
    auto issueB = [&](int kt) {
        const ushort* Bp = Bsrc + kt * 64;
        b0 = *(const uint4*)(Bp + (size_t)srow * C_ + soff);
        b1 = *(const uint4*)(Bp + (size_t)(32 + srow) * C_ + soff);
    };
    auto lwriteB = [&]() {
        *(uint4*)((char*)Bs + ((tid * 16) ^ swz)) = b0;
        *(uint4*)((char*)Bs + (((tid + 256) * 16) ^ swz)) = b1;
    };
    auto lda = [&](int kt, int mf, int ks) {
        return __builtin_bit_cast(bf16x8,
            *(const uint4*)(Arow + (size_t)mf * 16 * C_ + kt * 64 + ks * 32));
    };

    issueB(0);
    bf16x8 x00 = lda(0, 0, 0), x01 = lda(0, 0, 1), x10 = lda(0, 1, 0), x11 = lda(0, 1, 1);

    f32x4 acc[2][4] = {};
    for (int kt = 0; kt < 16; ++kt) {
        __syncthreads();                 // prev B readers done
        lwriteB();
        if (kt + 1 < 16) issueB(kt + 1);
        __syncthreads();                 // Bs ready
        const int ktn = (kt + 1 < 16) ? kt + 1 : kt;   // clamped: no OOB, no branch
        bf16x8 y00 = lda(ktn, 0, 0), y01 = lda(ktn, 0, 1);
        bf16x8 y10 = lda(ktn, 1, 0), y11 = lda(ktn, 1, 1);
#pragma unroll
        for (int ks = 0; ks < 2; ++ks) {
            bf16x8 bfr[4];
#pragma unroll
            for (int nf = 0; nf < 4; ++nf)
                bfr[nf] = lds_frag(Bs, nf * 16 + (lane & 15), ks * 64 + ((lane >> 4) << 4));
            bf16x8 a0f = ks ? x01 : x00;
            bf16x8 a1f = ks ? x11 : x10;
#pragma unroll
            for (int nf = 0; nf < 4; ++nf) {
                acc[0][nf] = mfma16(a0f, bfr[nf], acc[0][nf]);
                acc[1][nf] = mfma16(a1f, bfr[nf], acc[1][nf]);
            }
        }
        x00 = y00; x01 = y01; x10 = y10; x11 = y11;
    }

    // epilogue --------------------------------------------------------------
    const int sector = n0 >> 10;            // 0=q 1=k 2=v
    const int h = (n0 & 1023) >> 6;
    const float kc = hyp[h];
    const float inv_k = 1.0f / kc;
    float invf[2];
    invf[0] = __expf(-0.28782313662425572f * (float)(lane & 15));        // 10000^(-j/32)
    invf[1] = __expf(-0.28782313662425572f * (float)(16 + (lane & 15)));

#pragma unroll
    for (int mf = 0; mf < 2; ++mf) {
        float o[4][4];
#pragma unroll
        for (int nf = 0; nf < 4; ++nf)
#pragma unroll
            for (int r = 0; r < 4; ++r) o[nf][r] = acc[mf][nf][r];

        if (sector < 2) {
#pragma unroll
            for (int p = 0; p < 2; ++p) {
#pragma unroll
                for (int r = 0; r < 4; ++r) {
                    int m = m0 + wv * 32 + mf * 16 + ((lane >> 4) << 2) + r;
                    int t = m & (T_ - 1);
                    float sn, cs; __sincosf((float)t * invf[p], &sn, &cs);
                    float x1 = o[p][r], x2 = o[p + 2][r];
                    o[p][r]     =  x1 * cs + x2 * sn;
                    o[p + 2][r] = -x1 * sn + x2 * cs;
                }
            }
        }

#pragma unroll
        for (int r = 0; r < 4; ++r) {
            int m = m0 + wv * 32 + mf * 16 + ((lane >> 4) << 2) + r;
            int b = m >> 10, t = m & (T_ - 1);
            int bh = b * H_ + h;
            size_t base = ((size_t)bh * T_ + t) * HD_;
            float nrm = 0.f;
#pragma unroll
            for (int nf = 0; nf < 4; ++nf) {
                int d = nf * 16 + (lane & 15);
                float v = o[nf][r];
                nrm += v * v;
                ushort bv = f2bf(sector == 1 ? v * inv_k : v);
                if (sector == 0)      Qo[base + d] = bv;
                else if (sector == 1) Ko[base + d] = bv;
                else                  Vo[base + d] = bv;
            }
            if (sector < 2) {
#pragma unroll
                for (int mk = 1; mk < 16; mk <<= 1) nrm += __shfl_xor(nrm, mk);
                if ((lane & 15) == 0) {
                    float v0 = sqrtf(kc + nrm);
                    if (sector == 0) q0g[(size_t)bh * T_ + t] = v0;
                    else             k0g[(size_t)bh * T_ + t] = v0 * inv_k;
                }
            }
        }
    }
}

// ---------------------------------------------------------------------------
// Attention: paired q-tiles, fixed-max softmax. THIS ROUND: Ps halved to 4
// buffers (B then A reuse the same per-wave buffer — sequential use, intra-
// wave lgkmcnt handles WAR) -> LDS ~16.5KB -> 4 blocks/CU (was 2).
// ---------------------------------------------------------------------------
__global__ __launch_bounds__(256, 2) void attn_fwd(
    const ushort* __restrict__ Q, const ushort* __restrict__ K, const ushort* __restrict__ V,
    const float* __restrict__ q0g, const float* __restrict__ k0g,
    const float* __restrict__ hyp, ushort* __restrict__ AO)
{
    __shared__ ushort Ks[64 * 64];
    __shared__ ushort Vts[64 * 64];
    __shared__ ushort Ps[4][16 * 64];
    __shared__ float k0s[64];

    const int tid = threadIdx.x, lane = tid & 63, wv = tid >> 6;
    const int pr = blockIdx.x >> 6;
    const int bh = blockIdx.x & 63;
    const int h = bh & (H_ - 1);
    const int qa = pr, qb = 15 - pr, nt = qb + 1;
    const float c3 = sqrtf(hyp[h]) * 0.48045301391820142f;  // sqrt(k)*ln2^2
    const float e3 = 6.931471805599453e-07f;                // 1e-6*ln2

    const ushort* Kb = K + (size_t)bh * T_ * HD_;
    const ushort* Vb = V + (size_t)bh * T_ * HD_;

    bf16x8 aqA[2], aqB[2];
    {
        const ushort* qA = Q + ((size_t)bh * T_ + qa * 64 + wv * 16 + (lane & 15)) * HD_;
        const ushort* qB = Q + ((size_t)bh * T_ + qb * 64 + wv * 16 + (lane & 15)) * HD_;
#pragma unroll
        for (int ks = 0; ks < 2; ++ks) {
            aqA[ks] = __builtin_bit_cast(bf16x8, *(const uint4*)(qA + ks * 32 + ((lane >> 4) << 3)));
            aqB[ks] = __builtin_bit_cast(bf16x8, *(const uint4*)(qB + ks * 32 + ((lane >> 4) << 3)));
        }
    }
    float q0A[4], q0B[4];
#pragma unroll
    for (int r = 0; r < 4; ++r) {
        int rr = wv * 16 + ((lane >> 4) << 2) + r;
        q0A[r] = q0g[(size_t)bh * T_ + qa * 64 + rr];
        q0B[r] = q0g[(size_t)bh * T_ + qb * 64 + rr];
    }

    f32x4 oaccA[4] = {}, oaccB[4] = {};
    float lpA[4] = {}, lpB[4] = {};

    const int krow = tid >> 3, koff = tid & 7;
    const int sp = tid >> 3, dc = tid & 7;
    uint4 kv0, kv1, vv0, vv1;
    float kz = 0.f;
    auto issue = [&](int s0) {
        kv0 = *(const uint4*)(Kb + (size_t)(s0 + krow) * HD_ + koff * 8);
        kv1 = *(const uint4*)(Kb + (size_t)(s0 + 32 + krow) * HD_ + koff * 8);
        vv0 = *(const uint4*)(Vb + (size_t)(s0 + 2 * sp) * HD_ + dc * 8);
        vv1 = *(const uint4*)(Vb + (size_t)(s0 + 2 * sp + 1) * HD_ + dc * 8);
        if (tid < 64) kz = k0g[(size_t)bh * T_ + s0 + tid];
    };

    auto geom = [&](const f32x4* sc, const float* q0, const float* k0r, float p[4][4]) {
#pragma unroll
        for (int r = 0; r < 4; ++r)
#pragma unroll
            for (int sf = 0; sf < 4; ++sf) {
                float arg = fmaf(q0[r], k0r[sf], -sc[sf][r]);
                arg = fmaxf(arg, 1.0f + 1e-6f);
                float t = fmaf(arg, arg, -1.0f);
                float u = arg + __builtin_amdgcn_sqrtf(t);
                float l2 = __builtin_amdgcn_logf(u);
                float w2 = fmaf(l2, c3, e3);
                float rv = fminf(__builtin_amdgcn_rcpf(w2), 30.0f);
                p[sf][r] = __builtin_amdgcn_exp2f(rv);
            }
    };
    auto mask_diag = [&](float p[4][4]) {
        const int qloc = wv * 16 + ((lane >> 4) << 2);
#pragma unroll
        for (int r = 0; r < 4; ++r)
#pragma unroll
            for (int sf = 0; sf < 4; ++sf)
                if (sf * 16 + (lane & 15) > qloc + r) p[sf][r] = 0.f;
    };
    auto pv_step = [&](float p[4][4], ushort* ps, const bf16x8 (&vf)[2][4],
                       f32x4* oacc, float* lp) {
#pragma unroll
        for (int r = 0; r < 4; ++r) {
            int row = ((lane >> 4) << 2) + r;
#pragma unroll
            for (int sf = 0; sf < 4; ++sf) {
                int addr = (row * 128 + (sf * 16 + (lane & 15)) * 2) ^ (((row >> 2) & 3) << 5);
                *(ushort*)((char*)ps + addr) = f2bf(p[sf][r]);
            }
            lp[r] += (p[0][r] + p[1][r]) + (p[2][r] + p[3][r]);
        }
#pragma unroll
        for (int ks = 0; ks < 2; ++ks) {
            bf16x8 ap = lds_frag_p(ps, lane & 15, ks * 64 + ((lane >> 4) << 4));
#pragma unroll
            for (int df = 0; df < 4; ++df)
                oacc[df] = mfma16(ap, vf[ks][df], oacc[df]);
        }
    };

    issue(0);

    for (int it = 0; it < nt; ++it) {
        const bool actA = (it <= qa);
        __syncthreads();
        {
            *(uint4*)((char*)Ks + ((tid * 16) ^ ((krow & 7) << 4))) = kv0;
            int c1 = tid + 256;
            *(uint4*)((char*)Ks + ((c1 * 16) ^ (((c1 >> 3) & 7) << 4))) = kv1;
            union { uint4 v; ushort u[8]; } a, b;
            a.v = vv0; b.v = vv1;
#pragma unroll
            for (int j = 0; j < 8; ++j) {
                int d = dc * 8 + j;
                uint pack = (uint)a.u[j] | ((uint)b.u[j] << 16);
                *(uint*)((char*)Vts + ((d * 128 + sp * 4) ^ (((j ^ dc) & 7) << 4))) = pack;
            }
            if (tid < 64) k0s[tid] = kz;
        }
        if (it + 1 < nt) issue((it + 1) * 64);
        __syncthreads();

        bf16x8 bk[2][4];
#pragma unroll
        for (int ks = 0; ks < 2; ++ks)
#pragma unroll
            for (int sf = 0; sf < 4; ++sf)
                bk[ks][sf] = lds_frag(Ks, sf * 16 + (lane & 15), ks * 64 + ((lane >> 4) << 4));

        float k0r[4];
#pragma unroll
        for (int sf = 0; sf < 4; ++sf) k0r[sf] = k0s[sf * 16 + (lane & 15)];

        f32x4 scB[4] = {};
#pragma unroll
        for (int ks = 0; ks < 2; ++ks)
#pragma unroll
            for (int sf = 0; sf < 4; ++sf)
                scB[sf] = mfma16(aqB[ks], bk[ks][sf], scB[sf]);
        f32x4 scA[4] = {};
        if (actA) {
#pragma unroll
            for (int ks = 0; ks < 2; ++ks)
#pragma unroll
                for (int sf = 0; sf < 4; ++sf)
                    scA[sf] = mfma16(aqA[ks], bk[ks][sf], scA[sf]);
        }

        bf16x8 vf[2][4];
#pragma unroll
        for (int ks = 0; ks < 2; ++ks)
#pragma unroll
            for (int df = 0; df < 4; ++df)
                vf[ks][df] = lds_frag_v(Vts, df * 16 + (lane & 15), ks * 64 + ((lane >> 4) << 4));

        float pB[4][4];
        geom(scB, q0B, k0r, pB);
        if (it == qb) mask_diag(pB);
        pv_step(pB, Ps[wv], vf, oaccB, lpB);

        if (actA) {
            float pA[4][4];
            geom(scA, q0A, k0r, pA);
            if (it == qa) mask_diag(pA);
            pv_step(pA, Ps[wv], vf, oaccA, lpA);
        }
    }

    const int b = bh >> 4;
    auto epi = [&](f32x4* oacc, float* lp, int qt) {
#pragma unroll
        for (int r = 0; r < 4; ++r) {
            float s = lp[r];
#pragma unroll
            for (int mk = 1; mk < 16; mk <<= 1) s += __shfl_xor(s, mk);
            float invl = __builtin_amdgcn_rcpf(s);
            int t = qt * 64 + wv * 16 + ((lane >> 4) << 2) + r;
            size_t base = ((size_t)b * T_ + t) * C_ + h * HD_;
#pragma unroll
            for (int df = 0; df < 4; ++df)
                AO[base + df * 16 + (lane & 15)] = f2bf(oacc[df][r] * invl);
        }
    };
    epi(oaccA, lpA, qa);
    epi(oaccB, lpB, qb);
}

// ---------------------------------------------------------------------------
// GEMM2: out = attn @ W_out^T -> fp32. Same A-from-global structure
// (A = attn output, 8MB, L2-hot: written by attn_fwd immediately before).
// ---------------------------------------------------------------------------
__global__ __launch_bounds__(256) void gemm_out(
    const ushort* __restrict__ Ab, const ushort* __restrict__ Wb, float* __restrict__ Out)
{
    __shared__ ushort Bs[64 * 64];
    const int tid = threadIdx.x, lane = tid & 63, wv = tid >> 6;
    const int m0 = blockIdx.x * 128, n0 = blockIdx.y * 64;
    const ushort* Bsrc = Wb + (size_t)n0 * C_;
    const ushort* Arow = Ab + (size_t)(m0 + wv * 32 + (lane & 15)) * C_ + ((lane >> 4) << 3);

    const int srow = tid >> 3, soff = (tid & 7) * 8;
    const int swz = (srow & 7) << 4;
    uint4 b0, b1;
    auto issueB = [&](int kt) {
        const ushort* Bp = Bsrc + kt * 64;
        b0 = *(const uint4*)(Bp + (size_t)srow * C_ + soff);
        b1 = *(const uint4*)(Bp + (size_t)(32 + srow) * C_ + soff);
    };
    auto lwriteB = [&]() {
        *(uint4*)((char*)Bs + ((tid * 16) ^ swz)) = b0;
        *(uint4*)((char*)Bs + (((tid + 256) * 16) ^ swz)) = b1;
    };
    auto lda = [&](int kt, int mf, int ks) {
        return __builtin_bit_cast(bf16x8,
            *(const uint4*)(Arow + (size_t)mf * 16 * C_ + kt * 64 + ks * 32));
    };

    issueB(0);
    bf16x8 x00 = lda(0, 0, 0), x01 = lda(0, 0, 1), x10 = lda(0, 1, 0), x11 = lda(0, 1, 1);

    f32x4 acc[2][4] = {};
    for (int kt = 0; kt < 16; ++kt) {
        __syncthreads();
        lwriteB();
        if (kt + 1 < 16) issueB(kt + 1);
        __syncthreads();
        const int ktn = (kt + 1 < 16) ? kt + 1 : kt;
        bf16x8 y00 = lda(ktn, 0, 0), y01 = lda(ktn, 0, 1);
        bf16x8 y10 = lda(ktn, 1, 0), y11 = lda(ktn, 1, 1);
#pragma unroll
        for (int ks = 0; ks < 2; ++ks) {
            bf16x8 bfr[4];
#pragma unroll
            for (int nf = 0; nf < 4; ++nf)
                bfr[nf] = lds_frag(Bs, nf * 16 + (lane & 15), ks * 64 + ((lane >> 4) << 4));
            bf16x8 a0f = ks ? x01 : x00;
            bf16x8 a1f = ks ? x11 : x10;
#pragma unroll
            for (int nf = 0; nf < 4; ++nf) {
                acc[0][nf] = mfma16(a0f, bfr[nf], acc[0][nf]);
                acc[1][nf] = mfma16(a1f, bfr[nf], acc[1][nf]);
            }
        }
        x00 = y00; x01 = y01; x10 = y10; x11 = y11;
    }

#pragma unroll
    for (int mf = 0; mf < 2; ++mf)
#pragma unroll
        for (int r = 0; r < 4; ++r) {
            int m = m0 + wv * 32 + mf * 16 + ((lane >> 4) << 2) + r;
#pragma unroll
            for (int nf = 0; nf < 4; ++nf) {
                int n = n0 + nf * 16 + (lane & 15);
                Out[(size_t)m * C_ + n] = acc[mf][nf][r];
            }
        }
}

// ---------------------------------------------------------------------------
extern "C" void kernel_launch(void* const* d_in, const int* in_sizes, int n_in,
                              void* d_out, int out_size, void* d_ws, size_t ws_size,
                              hipStream_t stream)
{
    const float* x    = (const float*)d_in[0];
    const float* wqkv = (const float*)d_in[1];
    const float* wout = (const float*)d_in[2];
    const float* hyp  = (const float*)d_in[3];

    char* ws = (char*)d_ws;
    ushort* xb    = (ushort*)(ws + 0);
    ushort* wqkvb = (ushort*)(ws + 8388608);
    ushort* woutb = (ushort*)(ws + 14680064);
    ushort* Qb    = (ushort*)(ws + 16777216);
    ushort* Kb    = (ushort*)(ws + 25165824);
    ushort* Vb    = (ushort*)(ws + 33554432);
    ushort* Ab    = (ushort*)(ws + 41943040);
    float*  q0    = (float*)(ws + 50331648);
    float*  k0    = (float*)(ws + 50593792);

    cast_all<<<8192, 256, 0, stream>>>(x, wqkv, wout, xb, wqkvb, woutb);

    gemm_qkv<<<dim3(32, 48), 256, 0, stream>>>(xb, wqkvb, hyp, Qb, Kb, Vb, q0, k0);
    attn_fwd<<<512, 256, 0, stream>>>(Qb, Kb, Vb, q0, k0, hyp, Ab);
    gemm_out<<<dim3(32, 16), 256, 0, stream>>>(Ab, woutb, (float*)d_out);
}

// Round 13
// 96.238 us; speedup vs baseline: 1.2345x; 1.2345x over previous
//
#include <hip/hip_runtime.h>

#define B_ 4
#define T_ 1024
#define C_ 1024
#define H_ 16
#define HD_ 64

typedef short bf16x8 __attribute__((ext_vector_type(8)));
typedef float f32x4 __attribute__((ext_vector_type(4)));

__device__ __forceinline__ ushort f2bf(float f) {
    union { float f; unsigned u; } v; v.f = f;
    unsigned u = v.u;
    unsigned r = (u + 0x7fffu + ((u >> 16) & 1u)) >> 16;
    return (ushort)r;
}

__device__ __forceinline__ f32x4 mfma16(bf16x8 a, bf16x8 b, f32x4 c) {
    return __builtin_amdgcn_mfma_f32_16x16x32_bf16(a, b, c, 0, 0, 0);
}

// [rows][64] ushort tile, swizzle byte ^= (row&7)<<4 (K/A/B tiles).
__device__ __forceinline__ bf16x8 lds_frag(const ushort* base, int row, int byteoff) {
    int addr = (row * 128 + byteoff) ^ ((row & 7) << 4);
    uint4 u = *(const uint4*)((const char*)base + addr);
    return __builtin_bit_cast(bf16x8, u);
}

// V^T tile: byte ^= (((d&7)^(d>>3))&7)<<4.
__device__ __forceinline__ bf16x8 lds_frag_v(const ushort* base, int d, int byteoff) {
    int addr = (d * 128 + byteoff) ^ ((((d & 7) ^ (d >> 3)) & 7) << 4);
    uint4 u = *(const uint4*)((const char*)base + addr);
    return __builtin_bit_cast(bf16x8, u);
}

// P tile (16 rows): swizzle ((row>>2)&3)<<5.
__device__ __forceinline__ bf16x8 lds_frag_p(const ushort* base, int row, int byteoff) {
    int addr = (row * 128 + byteoff) ^ (((row >> 2) & 3) << 5);
    uint4 u = *(const uint4*)((const char*)base + addr);
    return __builtin_bit_cast(bf16x8, u);
}

// Raw barriers (T4): __syncthreads() emits s_waitcnt vmcnt(0) before s_barrier,
// which DRAINS in-flight prefetch loads every iter — the r3/r9/r11 "prefetch"
// never actually overlapped compute. These keep vmcnt untouched.
__device__ __forceinline__ void bar_plain() {
    __builtin_amdgcn_sched_barrier(0);
    __builtin_amdgcn_s_barrier();
    __builtin_amdgcn_sched_barrier(0);
}
__device__ __forceinline__ void bar_lds() {   // after LDS writes: visibility only
    asm volatile("s_waitcnt lgkmcnt(0)" ::: "memory");
    __builtin_amdgcn_sched_barrier(0);
    __builtin_amdgcn_s_barrier();
    __builtin_amdgcn_sched_barrier(0);
}

// One fused cast kernel for all three fp32->bf16 conversions.
__global__ void cast_all(const float* __restrict__ x, const float* __restrict__ wqkv,
                         const float* __restrict__ wout,
                         ushort* __restrict__ xb, ushort* __restrict__ wqkvb,
                         ushort* __restrict__ woutb) {
    int i = (blockIdx.x * 256 + threadIdx.x) * 4;
    const float* src; ushort* dst; int off;
    if (i < 4194304)      { src = x;    dst = xb;    off = i; }
    else if (i < 7340032) { src = wqkv; dst = wqkvb; off = i - 4194304; }
    else                  { src = wout; dst = woutb; off = i - 7340032; }
    float4 v = *(const float4*)(src + off);
    ushort4 o = make_ushort4(f2bf(v.x), f2bf(v.y), f2bf(v.z), f2bf(v.w));
    *(ushort4*)(dst + off) = o;
}

// ---------------------------------------------------------------------------
// GEMM core: block 128(M) x 64(N), BK=64, 4 waves each 32x64 (r11 config).
// 2-deep named-reg prefetch + RAW barriers so the prefetch truly stays in
// flight across barriers (consumer-side counted vmcnt is compiler-inserted
// at the next lwrite's register use). Tail peeled: hot loop unconditional.
// ---------------------------------------------------------------------------
#define GEMM_COMPUTE_128x64(As, Bs)                                                       \
    {                                                                                     \
        _Pragma("unroll")                                                                 \
        for (int ks = 0; ks < 2; ++ks) {                                                  \
            bf16x8 af[2], bfr[4];                                                         \
            _Pragma("unroll")                                                             \
            for (int mf = 0; mf < 2; ++mf)                                                \
                af[mf] = lds_frag(As, wv * 32 + mf * 16 + (lane & 15),                    \
                                  ks * 64 + ((lane >> 4) << 4));                          \
            _Pragma("unroll")                                                             \
            for (int nf = 0; nf < 4; ++nf)                                                \
                bfr[nf] = lds_frag(Bs, nf * 16 + (lane & 15),                             \
                                   ks * 64 + ((lane >> 4) << 4));                         \
            _Pragma("unroll")                                                             \
            for (int mf = 0; mf < 2; ++mf)                                                \
                _Pragma("unroll")                                                         \
                for (int nf = 0; nf < 4; ++nf)                                            \
                    acc[mf][nf] = mfma16(af[mf], bfr[nf], acc[mf][nf]);                   \
        }                                                                                 \
    }

#define GEMM_STAGING(Asrc, Bsrc)                                                          \
    const int srow = tid >> 3, soff = (tid & 7) * 8;                                      \
    const int swz = (srow & 7) << 4;                                                      \
    uint4 a0, a1, a2, a3, b0, b1;                                                         \
    uint4 c0, c1, c2, c3, d0, d1;                                                         \
    auto issueA = [&](int kt) {                                                           \
        const ushort* Ap = Asrc + kt * 64;                                                \
        const ushort* Bp = Bsrc + kt * 64;                                                \
        a0 = *(const uint4*)(Ap + (size_t)srow * C_ + soff);                              \
        a1 = *(const uint4*)(Ap + (size_t)(32 + srow) * C_ + soff);                       \
        a2 = *(const uint4*)(Ap + (size_t)(64 + srow) * C_ + soff);                       \
        a3 = *(const uint4*)(Ap + (size_t)(96 + srow) * C_ + soff);                       \
        b0 = *(const uint4*)(Bp + (size_t)srow * C_ + soff);                              \
        b1 = *(const uint4*)(Bp + (size_t)(32 + srow) * C_ + soff);                       \
    };                                                                                    \
    auto issueB = [&](int kt) {                                                           \
        const ushort* Ap = Asrc + kt * 64;                                                \
        const ushort* Bp = Bsrc + kt * 64;                                                \
        c0 = *(const uint4*)(Ap + (size_t)srow * C_ + soff);                              \
        c1 = *(const uint4*)(Ap + (size_t)(32 + srow) * C_ + soff);                       \
        c2 = *(const uint4*)(Ap + (size_t)(64 + srow) * C_ + soff);                       \
        c3 = *(const uint4*)(Ap + (size_t)(96 + srow) * C_ + soff);                       \
        d0 = *(const uint4*)(Bp + (size_t)srow * C_ + soff);                              \
        d1 = *(const uint4*)(Bp + (size_t)(32 + srow) * C_ + soff);                       \
    };                                                                                    \
    auto lwriteA = [&]() {                                                                \
        *(uint4*)((char*)As + ((tid * 16) ^ swz)) = a0;                                   \
        *(uint4*)((char*)As + (((tid + 256) * 16) ^ swz)) = a1;                           \
        *(uint4*)((char*)As + (((tid + 512) * 16) ^ swz)) = a2;                           \
        *(uint4*)((char*)As + (((tid + 768) * 16) ^ swz)) = a3;                           \
        *(uint4*)((char*)Bs + ((tid * 16) ^ swz)) = b0;                                   \
        *(uint4*)((char*)Bs + (((tid + 256) * 16) ^ swz)) = b1;                           \
    };                                                                                    \
    auto lwriteB = [&]() {                                                                \
        *(uint4*)((char*)As + ((tid * 16) ^ swz)) = c0;                                   \
        *(uint4*)((char*)As + (((tid + 256) * 16) ^ swz)) = c1;                           \
        *(uint4*)((char*)As + (((tid + 512) * 16) ^ swz)) = c2;                           \
        *(uint4*)((char*)As + (((tid + 768) * 16) ^ swz)) = c3;                           \
        *(uint4*)((char*)Bs + ((tid * 16) ^ swz)) = d0;                                   \
        *(uint4*)((char*)Bs + (((tid + 256) * 16) ^ swz)) = d1;                           \
    }

// hot loop: kt = 0..12 step 2, unconditional issues (kt+2<=14, kt+3<=15);
// tail kt=14 has no issues. No vmcnt(0) anywhere in the loop.
#define GEMM_MAIN_LOOP()                                                                  \
    issueA(0); issueB(1);                                                                 \
    for (int kt = 0; kt < 14; kt += 2) {                                                  \
        bar_plain();                                                                      \
        lwriteA();                                                                        \
        issueA(kt + 2);                                                                   \
        bar_lds();                                                                        \
        GEMM_COMPUTE_128x64(As, Bs);                                                      \
        bar_plain();                                                                      \
        lwriteB();                                                                        \
        issueB(kt + 3);                                                                   \
        bar_lds();                                                                        \
        GEMM_COMPUTE_128x64(As, Bs);                                                      \
    }                                                                                     \
    bar_plain();                                                                          \
    lwriteA();                                                                            \
    bar_lds();                                                                            \
    GEMM_COMPUTE_128x64(As, Bs);                                                          \
    bar_plain();                                                                          \
    lwriteB();                                                                            \
    bar_lds();                                                                            \
    GEMM_COMPUTE_128x64(As, Bs);

// ---------------------------------------------------------------------------
// GEMM1: qkv = x @ W_qkv^T, fused RoPE + norms + kappa-prescale.
// Grid (32 m, 48 n) x-major. N-tile = 64 = one (sector, head).
// ---------------------------------------------------------------------------
__global__ __launch_bounds__(256) void gemm_qkv(
    const ushort* __restrict__ Xb, const ushort* __restrict__ Wb,
    const float* __restrict__ hyp,
    ushort* __restrict__ Qo, ushort* __restrict__ Ko, ushort* __restrict__ Vo,
    float* __restrict__ q0g, float* __restrict__ k0g)
{
    __shared__ ushort As[128 * 64];
    __shared__ ushort Bs[64 * 64];
    const int tid = threadIdx.x, lane = tid & 63, wv = tid >> 6;
    const int m0 = blockIdx.x * 128, n0 = blockIdx.y * 64;
    const ushort* Asrc = Xb + (size_t)m0 * C_;
    const ushort* Bsrc = Wb + (size_t)n0 * C_;

    GEMM_STAGING(Asrc, Bsrc);

    f32x4 acc[2][4] = {};
    GEMM_MAIN_LOOP();

    // epilogue --------------------------------------------------------------
    const int sector = n0 >> 10;            // 0=q 1=k 2=v
    const int h = (n0 & 1023) >> 6;
    const float kc = hyp[h];
    const float inv_k = 1.0f / kc;
    float invf[2];
    invf[0] = __expf(-0.28782313662425572f * (float)(lane & 15));        // 10000^(-j/32)
    invf[1] = __expf(-0.28782313662425572f * (float)(16 + (lane & 15)));

#pragma unroll
    for (int mf = 0; mf < 2; ++mf) {
        float o[4][4];
#pragma unroll
        for (int nf = 0; nf < 4; ++nf)
#pragma unroll
            for (int r = 0; r < 4; ++r) o[nf][r] = acc[mf][nf][r];

        if (sector < 2) {
#pragma unroll
            for (int p = 0; p < 2; ++p) {
#pragma unroll
                for (int r = 0; r < 4; ++r) {
                    int m = m0 + wv * 32 + mf * 16 + ((lane >> 4) << 2) + r;
                    int t = m & (T_ - 1);
                    float sn, cs; __sincosf((float)t * invf[p], &sn, &cs);
                    float x1 = o[p][r], x2 = o[p + 2][r];
                    o[p][r]     =  x1 * cs + x2 * sn;
                    o[p + 2][r] = -x1 * sn + x2 * cs;
                }
            }
        }

#pragma unroll
        for (int r = 0; r < 4; ++r) {
            int m = m0 + wv * 32 + mf * 16 + ((lane >> 4) << 2) + r;
            int b = m >> 10, t = m & (T_ - 1);
            int bh = b * H_ + h;
            size_t base = ((size_t)bh * T_ + t) * HD_;
            float nrm = 0.f;
#pragma unroll
            for (int nf = 0; nf < 4; ++nf) {
                int d = nf * 16 + (lane & 15);
                float v = o[nf][r];
                nrm += v * v;
                ushort bv = f2bf(sector == 1 ? v * inv_k : v);
                if (sector == 0)      Qo[base + d] = bv;
                else if (sector == 1) Ko[base + d] = bv;
                else                  Vo[base + d] = bv;
            }
            if (sector < 2) {
#pragma unroll
                for (int mk = 1; mk < 16; mk <<= 1) nrm += __shfl_xor(nrm, mk);
                if ((lane & 15) == 0) {
                    float v0 = sqrtf(kc + nrm);
                    if (sector == 0) q0g[(size_t)bh * T_ + t] = v0;
                    else             k0g[(size_t)bh * T_ + t] = v0 * inv_k;
                }
            }
        }
    }
}

// ---------------------------------------------------------------------------
// Attention (r11 exact, proven): paired q-tiles, fixed-max softmax.
// ---------------------------------------------------------------------------
__global__ __launch_bounds__(256, 2) void attn_fwd(
    const ushort* __restrict__ Q, const ushort* __restrict__ K, const ushort* __restrict__ V,
    const float* __restrict__ q0g, const float* __restrict__ k0g,
    const float* __restrict__ hyp, ushort* __restrict__ AO)
{
    __shared__ ushort Ks[64 * 64];
    __shared__ ushort Vts[64 * 64];
    __shared__ ushort Ps[8][16 * 64];
    __shared__ float k0s[64];

    const int tid = threadIdx.x, lane = tid & 63, wv = tid >> 6;
    const int pr = blockIdx.x >> 6;
    const int bh = blockIdx.x & 63;
    const int h = bh & (H_ - 1);
    const int qa = pr, qb = 15 - pr, nt = qb + 1;
    const float c3 = sqrtf(hyp[h]) * 0.48045301391820142f;  // sqrt(k)*ln2^2
    const float e3 = 6.931471805599453e-07f;                // 1e-6*ln2

    const ushort* Kb = K + (size_t)bh * T_ * HD_;
    const ushort* Vb = V + (size_t)bh * T_ * HD_;

    bf16x8 aqA[2], aqB[2];
    {
        const ushort* qA = Q + ((size_t)bh * T_ + qa * 64 + wv * 16 + (lane & 15)) * HD_;
        const ushort* qB = Q + ((size_t)bh * T_ + qb * 64 + wv * 16 + (lane & 15)) * HD_;
#pragma unroll
        for (int ks = 0; ks < 2; ++ks) {
            aqA[ks] = __builtin_bit_cast(bf16x8, *(const uint4*)(qA + ks * 32 + ((lane >> 4) << 3)));
            aqB[ks] = __builtin_bit_cast(bf16x8, *(const uint4*)(qB + ks * 32 + ((lane >> 4) << 3)));
        }
    }
    float q0A[4], q0B[4];
#pragma unroll
    for (int r = 0; r < 4; ++r) {
        int rr = wv * 16 + ((lane >> 4) << 2) + r;
        q0A[r] = q0g[(size_t)bh * T_ + qa * 64 + rr];
        q0B[r] = q0g[(size_t)bh * T_ + qb * 64 + rr];
    }

    f32x4 oaccA[4] = {}, oaccB[4] = {};
    float lpA[4] = {}, lpB[4] = {};

    const int krow = tid >> 3, koff = tid & 7;
    const int sp = tid >> 3, dc = tid & 7;
    uint4 kv0, kv1, vv0, vv1;
    float kz = 0.f;
    auto issue = [&](int s0) {
        kv0 = *(const uint4*)(Kb + (size_t)(s0 + krow) * HD_ + koff * 8);
        kv1 = *(const uint4*)(Kb + (size_t)(s0 + 32 + krow) * HD_ + koff * 8);
        vv0 = *(const uint4*)(Vb + (size_t)(s0 + 2 * sp) * HD_ + dc * 8);
        vv1 = *(const uint4*)(Vb + (size_t)(s0 + 2 * sp + 1) * HD_ + dc * 8);
        if (tid < 64) kz = k0g[(size_t)bh * T_ + s0 + tid];
    };

    auto geom = [&](const f32x4* sc, const float* q0, const float* k0r, float p[4][4]) {
#pragma unroll
        for (int r = 0; r < 4; ++r)
#pragma unroll
            for (int sf = 0; sf < 4; ++sf) {
                float arg = fmaf(q0[r], k0r[sf], -sc[sf][r]);
                arg = fmaxf(arg, 1.0f + 1e-6f);
                float t = fmaf(arg, arg, -1.0f);
                float u = arg + __builtin_amdgcn_sqrtf(t);
                float l2 = __builtin_amdgcn_logf(u);
                float w2 = fmaf(l2, c3, e3);
                float rv = fminf(__builtin_amdgcn_rcpf(w2), 30.0f);
                p[sf][r] = __builtin_amdgcn_exp2f(rv);
            }
    };
    auto mask_diag = [&](float p[4][4]) {
        const int qloc = wv * 16 + ((lane >> 4) << 2);
#pragma unroll
        for (int r = 0; r < 4; ++r)
#pragma unroll
            for (int sf = 0; sf < 4; ++sf)
                if (sf * 16 + (lane & 15) > qloc + r) p[sf][r] = 0.f;
    };
    auto pv_step = [&](float p[4][4], ushort* ps, const bf16x8 (&vf)[2][4],
                       f32x4* oacc, float* lp) {
#pragma unroll
        for (int r = 0; r < 4; ++r) {
            int row = ((lane >> 4) << 2) + r;
#pragma unroll
            for (int sf = 0; sf < 4; ++sf) {
                int addr = (row * 128 + (sf * 16 + (lane & 15)) * 2) ^ (((row >> 2) & 3) << 5);
                *(ushort*)((char*)ps + addr) = f2bf(p[sf][r]);
            }
            lp[r] += (p[0][r] + p[1][r]) + (p[2][r] + p[3][r]);
        }
#pragma unroll
        for (int ks = 0; ks < 2; ++ks) {
            bf16x8 ap = lds_frag_p(ps, lane & 15, ks * 64 + ((lane >> 4) << 4));
#pragma unroll
            for (int df = 0; df < 4; ++df)
                oacc[df] = mfma16(ap, vf[ks][df], oacc[df]);
        }
    };

    issue(0);

    for (int it = 0; it < nt; ++it) {
        const bool actA = (it <= qa);
        __syncthreads();
        {
            *(uint4*)((char*)Ks + ((tid * 16) ^ ((krow & 7) << 4))) = kv0;
            int c1 = tid + 256;
            *(uint4*)((char*)Ks + ((c1 * 16) ^ (((c1 >> 3) & 7) << 4))) = kv1;
            union { uint4 v; ushort u[8]; } a, b;
            a.v = vv0; b.v = vv1;
#pragma unroll
            for (int j = 0; j < 8; ++j) {
                int d = dc * 8 + j;
                uint pack = (uint)a.u[j] | ((uint)b.u[j] << 16);
                *(uint*)((char*)Vts + ((d * 128 + sp * 4) ^ (((j ^ dc) & 7) << 4))) = pack;
            }
            if (tid < 64) k0s[tid] = kz;
        }
        if (it + 1 < nt) issue((it + 1) * 64);
        __syncthreads();

        bf16x8 bk[2][4];
#pragma unroll
        for (int ks = 0; ks < 2; ++ks)
#pragma unroll
            for (int sf = 0; sf < 4; ++sf)
                bk[ks][sf] = lds_frag(Ks, sf * 16 + (lane & 15), ks * 64 + ((lane >> 4) << 4));

        float k0r[4];
#pragma unroll
        for (int sf = 0; sf < 4; ++sf) k0r[sf] = k0s[sf * 16 + (lane & 15)];

        f32x4 scB[4] = {};
#pragma unroll
        for (int ks = 0; ks < 2; ++ks)
#pragma unroll
            for (int sf = 0; sf < 4; ++sf)
                scB[sf] = mfma16(aqB[ks], bk[ks][sf], scB[sf]);
        f32x4 scA[4] = {};
        if (actA) {
#pragma unroll
            for (int ks = 0; ks < 2; ++ks)
#pragma unroll
                for (int sf = 0; sf < 4; ++sf)
                    scA[sf] = mfma16(aqA[ks], bk[ks][sf], scA[sf]);
        }

        bf16x8 vf[2][4];
#pragma unroll
        for (int ks = 0; ks < 2; ++ks)
#pragma unroll
            for (int df = 0; df < 4; ++df)
                vf[ks][df] = lds_frag_v(Vts, df * 16 + (lane & 15), ks * 64 + ((lane >> 4) << 4));

        float pB[4][4];
        geom(scB, q0B, k0r, pB);
        if (it == qb) mask_diag(pB);
        pv_step(pB, Ps[wv * 2 + 1], vf, oaccB, lpB);

        if (actA) {
            float pA[4][4];
            geom(scA, q0A, k0r, pA);
            if (it == qa) mask_diag(pA);
            pv_step(pA, Ps[wv * 2 + 0], vf, oaccA, lpA);
        }
    }

    const int b = bh >> 4;
    auto epi = [&](f32x4* oacc, float* lp, int qt) {
#pragma unroll
        for (int r = 0; r < 4; ++r) {
            float s = lp[r];
#pragma unroll
            for (int mk = 1; mk < 16; mk <<= 1) s += __shfl_xor(s, mk);
            float invl = __builtin_amdgcn_rcpf(s);
            int t = qt * 64 + wv * 16 + ((lane >> 4) << 2) + r;
            size_t base = ((size_t)b * T_ + t) * C_ + h * HD_;
#pragma unroll
            for (int df = 0; df < 4; ++df)
                AO[base + df * 16 + (lane & 15)] = f2bf(oacc[df][r] * invl);
        }
    };
    epi(oaccA, lpA, qa);
    epi(oaccB, lpB, qb);
}

// ---------------------------------------------------------------------------
// GEMM2: out = attn @ W_out^T -> fp32. Same raw-barrier 2-deep structure.
// ---------------------------------------------------------------------------
__global__ __launch_bounds__(256) void gemm_out(
    const ushort* __restrict__ Ab, const ushort* __restrict__ Wb, float* __restrict__ Out)
{
    __shared__ ushort As[128 * 64];
    __shared__ ushort Bs[64 * 64];
    const int tid = threadIdx.x, lane = tid & 63, wv = tid >> 6;
    const int m0 = blockIdx.x * 128, n0 = blockIdx.y * 64;
    const ushort* Asrc = Ab + (size_t)m0 * C_;
    const ushort* Bsrc = Wb + (size_t)n0 * C_;

    GEMM_STAGING(Asrc, Bsrc);

    f32x4 acc[2][4] = {};
    GEMM_MAIN_LOOP();

#pragma unroll
    for (int mf = 0; mf < 2; ++mf)
#pragma unroll
        for (int r = 0; r < 4; ++r) {
            int m = m0 + wv * 32 + mf * 16 + ((lane >> 4) << 2) + r;
#pragma unroll
            for (int nf = 0; nf < 4; ++nf) {
                int n = n0 + nf * 16 + (lane & 15);
                Out[(size_t)m * C_ + n] = acc[mf][nf][r];
            }
        }
}

// ---------------------------------------------------------------------------
extern "C" void kernel_launch(void* const* d_in, const int* in_sizes, int n_in,
                              void* d_out, int out_size, void* d_ws, size_t ws_size,
                              hipStream_t stream)
{
    const float* x    = (const float*)d_in[0];
    const float* wqkv = (const float*)d_in[1];
    const float* wout = (const float*)d_in[2];
    const float* hyp  = (const float*)d_in[3];

    char* ws = (char*)d_ws;
    ushort* xb    = (ushort*)(ws + 0);
    ushort* wqkvb = (ushort*)(ws + 8388608);
    ushort* woutb = (ushort*)(ws + 14680064);
    ushort* Qb    = (ushort*)(ws + 16777216);
    ushort* Kb    = (ushort*)(ws + 25165824);
    ushort* Vb    = (ushort*)(ws + 33554432);
    ushort* Ab    = (ushort*)(ws + 41943040);
    float*  q0    = (float*)(ws + 50331648);
    float*  k0    = (float*)(ws + 50593792);

    cast_all<<<8192, 256, 0, stream>>>(x, wqkv, wout, xb, wqkvb, woutb);

    gemm_qkv<<<dim3(32, 48), 256, 0, stream>>>(xb, wqkvb, hyp, Qb, Kb, Vb, q0, k0);
    attn_fwd<<<512, 256, 0, stream>>>(Qb, Kb, Vb, q0, k0, hyp, Ab);
    gemm_out<<<dim3(32, 16), 256, 0, stream>>>(Ab, woutb, (float*)d_out);
}

// Round 14
// 95.503 us; speedup vs baseline: 1.2440x; 1.0077x over previous
//
#include <hip/hip_runtime.h>

#define B_ 4
#define T_ 1024
#define C_ 1024
#define H_ 16
#define HD_ 64

typedef short bf16x8 __attribute__((ext_vector_type(8)));
typedef float f32x4 __attribute__((ext_vector_type(4)));

__device__ __forceinline__ ushort f2bf(float f) {
    union { float f; unsigned u; } v; v.f = f;
    unsigned u = v.u;
    unsigned r = (u + 0x7fffu + ((u >> 16) & 1u)) >> 16;
    return (ushort)r;
}

__device__ __forceinline__ f32x4 mfma16(bf16x8 a, bf16x8 b, f32x4 c) {
    return __builtin_amdgcn_mfma_f32_16x16x32_bf16(a, b, c, 0, 0, 0);
}

// [rows][64] ushort tile, swizzle byte ^= (row&7)<<4 (K/A/B tiles).
__device__ __forceinline__ bf16x8 lds_frag(const ushort* base, int row, int byteoff) {
    int addr = (row * 128 + byteoff) ^ ((row & 7) << 4);
    uint4 u = *(const uint4*)((const char*)base + addr);
    return __builtin_bit_cast(bf16x8, u);
}

// V^T tile: byte ^= (((d&7)^(d>>3))&7)<<4.
__device__ __forceinline__ bf16x8 lds_frag_v(const ushort* base, int d, int byteoff) {
    int addr = (d * 128 + byteoff) ^ ((((d & 7) ^ (d >> 3)) & 7) << 4);
    uint4 u = *(const uint4*)((const char*)base + addr);
    return __builtin_bit_cast(bf16x8, u);
}

// P tile (16 rows): swizzle ((row>>2)&3)<<5.
__device__ __forceinline__ bf16x8 lds_frag_p(const ushort* base, int row, int byteoff) {
    int addr = (row * 128 + byteoff) ^ (((row >> 2) & 3) << 5);
    uint4 u = *(const uint4*)((const char*)base + addr);
    return __builtin_bit_cast(bf16x8, u);
}

// Raw barrier: lgkmcnt(0) for LDS-write visibility, no vmcnt drain.
__device__ __forceinline__ void bar_lds() {
    asm volatile("s_waitcnt lgkmcnt(0)" ::: "memory");
    __builtin_amdgcn_sched_barrier(0);
    __builtin_amdgcn_s_barrier();
    __builtin_amdgcn_sched_barrier(0);
}

// One fused cast kernel for all three fp32->bf16 conversions.
__global__ void cast_all(const float* __restrict__ x, const float* __restrict__ wqkv,
                         const float* __restrict__ wout,
                         ushort* __restrict__ xb, ushort* __restrict__ wqkvb,
                         ushort* __restrict__ woutb) {
    int i = (blockIdx.x * 256 + threadIdx.x) * 4;
    const float* src; ushort* dst; int off;
    if (i < 4194304)      { src = x;    dst = xb;    off = i; }
    else if (i < 7340032) { src = wqkv; dst = wqkvb; off = i - 4194304; }
    else                  { src = wout; dst = woutb; off = i - 7340032; }
    float4 v = *(const float4*)(src + off);
    ushort4 o = make_ushort4(f2bf(v.x), f2bf(v.y), f2bf(v.z), f2bf(v.w));
    *(ushort4*)(dst + off) = o;
}

// ---------------------------------------------------------------------------
// GEMM core: block 128(M) x 64(N), BK=64, 4 waves each 32x64.
// ROUND 14: LDS DOUBLE-BUFFER + ONE raw barrier per K-iter. Four schedules
// (r3/r9/r11/r13) all hit ~51us with 2 barriers/iter: the serialized
// write->bar->read skeleton was the invariant. With dbuf, writes to buf^1
// overlap compute on buf^0 (no hazard), barrier count halves (32->16).
// Hazards: writes(buf1,iter k, pre-bar_k) vs reads(buf1,iter k+1, post-bar_k)
// separated; writes(buf0,iter k+1, post-bar_k) vs reads(buf0,iter k, pre-
// bar_k) separated. 1-deep named-reg staging (struct form spills: r5/6/8).
// ---------------------------------------------------------------------------
#define GEMM_COMPUTE_128x64(As, Bs)                                                       \
    {                                                                                     \
        _Pragma("unroll")                                                                 \
        for (int ks = 0; ks < 2; ++ks) {                                                  \
            bf16x8 af[2], bfr[4];                                                         \
            _Pragma("unroll")                                                             \
            for (int mf = 0; mf < 2; ++mf)                                                \
                af[mf] = lds_frag(As, wv * 32 + mf * 16 + (lane & 15),                    \
                                  ks * 64 + ((lane >> 4) << 4));                          \
            _Pragma("unroll")                                                             \
            for (int nf = 0; nf < 4; ++nf)                                                \
                bfr[nf] = lds_frag(Bs, nf * 16 + (lane & 15),                             \
                                   ks * 64 + ((lane >> 4) << 4));                         \
            _Pragma("unroll")                                                             \
            for (int mf = 0; mf < 2; ++mf)                                                \
                _Pragma("unroll")                                                         \
                for (int nf = 0; nf < 4; ++nf)                                            \
                    acc[mf][nf] = mfma16(af[mf], bfr[nf], acc[mf][nf]);                   \
        }                                                                                 \
    }

#define GEMM_DBUF_STAGING(Asrc, Bsrc)                                                     \
    const int srow = tid >> 3, soff = (tid & 7) * 8;                                      \
    const int swz = (srow & 7) << 4;                                                      \
    uint4 a0, a1, a2, a3, b0, b1;                                                         \
    auto issue = [&](int kt) {                                                            \
        const ushort* Ap = Asrc + kt * 64;                                                \
        const ushort* Bp = Bsrc + kt * 64;                                                \
        a0 = *(const uint4*)(Ap + (size_t)srow * C_ + soff);                              \
        a1 = *(const uint4*)(Ap + (size_t)(32 + srow) * C_ + soff);                       \
        a2 = *(const uint4*)(Ap + (size_t)(64 + srow) * C_ + soff);                       \
        a3 = *(const uint4*)(Ap + (size_t)(96 + srow) * C_ + soff);                       \
        b0 = *(const uint4*)(Bp + (size_t)srow * C_ + soff);                              \
        b1 = *(const uint4*)(Bp + (size_t)(32 + srow) * C_ + soff);                       \
    };                                                                                    \
    auto lwrite = [&](ushort* Ad, ushort* Bd) {                                           \
        *(uint4*)((char*)Ad + ((tid * 16) ^ swz)) = a0;                                   \
        *(uint4*)((char*)Ad + (((tid + 256) * 16) ^ swz)) = a1;                           \
        *(uint4*)((char*)Ad + (((tid + 512) * 16) ^ swz)) = a2;                           \
        *(uint4*)((char*)Ad + (((tid + 768) * 16) ^ swz)) = a3;                           \
        *(uint4*)((char*)Bd + ((tid * 16) ^ swz)) = b0;                                   \
        *(uint4*)((char*)Bd + (((tid + 256) * 16) ^ swz)) = b1;                           \
    }

// Invariant at pair entry: buf0 = tile kt, regs = tile kt+1.
// Loop covers tiles 0..11; peeled tail covers 12..15 (issues stay in-bounds).
#define GEMM_DBUF_LOOP()                                                                  \
    issue(0);                                                                             \
    lwrite(As0, Bs0);                                                                     \
    issue(1);                                                                             \
    bar_lds();                                                                            \
    for (int kt = 0; kt < 12; kt += 2) {                                                  \
        lwrite(As1, Bs1);                                                                 \
        issue(kt + 2);                                                                    \
        GEMM_COMPUTE_128x64(As0, Bs0);                                                    \
        bar_lds();                                                                        \
        lwrite(As0, Bs0);                                                                 \
        issue(kt + 3);                                                                    \
        GEMM_COMPUTE_128x64(As1, Bs1);                                                    \
        bar_lds();                                                                        \
    }                                                                                     \
    lwrite(As1, Bs1);            /* tile 13 */                                            \
    issue(14);                                                                            \
    GEMM_COMPUTE_128x64(As0, Bs0);   /* tile 12 */                                        \
    bar_lds();                                                                            \
    lwrite(As0, Bs0);            /* tile 14 */                                            \
    issue(15);                                                                            \
    GEMM_COMPUTE_128x64(As1, Bs1);   /* tile 13 */                                        \
    bar_lds();                                                                            \
    lwrite(As1, Bs1);            /* tile 15 */                                            \
    GEMM_COMPUTE_128x64(As0, Bs0);   /* tile 14 */                                        \
    bar_lds();                                                                            \
    GEMM_COMPUTE_128x64(As1, Bs1);   /* tile 15 */

// ---------------------------------------------------------------------------
// GEMM1: qkv = x @ W_qkv^T, fused RoPE + norms + kappa-prescale.
// Grid (32 m, 48 n) x-major. N-tile = 64 = one (sector, head).
// ---------------------------------------------------------------------------
__global__ __launch_bounds__(256) void gemm_qkv(
    const ushort* __restrict__ Xb, const ushort* __restrict__ Wb,
    const float* __restrict__ hyp,
    ushort* __restrict__ Qo, ushort* __restrict__ Ko, ushort* __restrict__ Vo,
    float* __restrict__ q0g, float* __restrict__ k0g)
{
    __shared__ ushort As0[128 * 64], Bs0[64 * 64];
    __shared__ ushort As1[128 * 64], Bs1[64 * 64];
    const int tid = threadIdx.x, lane = tid & 63, wv = tid >> 6;
    const int m0 = blockIdx.x * 128, n0 = blockIdx.y * 64;
    const ushort* Asrc = Xb + (size_t)m0 * C_;
    const ushort* Bsrc = Wb + (size_t)n0 * C_;

    GEMM_DBUF_STAGING(Asrc, Bsrc);

    f32x4 acc[2][4] = {};
    GEMM_DBUF_LOOP();

    // epilogue --------------------------------------------------------------
    const int sector = n0 >> 10;            // 0=q 1=k 2=v
    const int h = (n0 & 1023) >> 6;
    const float kc = hyp[h];
    const float inv_k = 1.0f / kc;
    float invf[2];
    invf[0] = __expf(-0.28782313662425572f * (float)(lane & 15));        // 10000^(-j/32)
    invf[1] = __expf(-0.28782313662425572f * (float)(16 + (lane & 15)));

#pragma unroll
    for (int mf = 0; mf < 2; ++mf) {
        float o[4][4];
#pragma unroll
        for (int nf = 0; nf < 4; ++nf)
#pragma unroll
            for (int r = 0; r < 4; ++r) o[nf][r] = acc[mf][nf][r];

        if (sector < 2) {
#pragma unroll
            for (int p = 0; p < 2; ++p) {
#pragma unroll
                for (int r = 0; r < 4; ++r) {
                    int m = m0 + wv * 32 + mf * 16 + ((lane >> 4) << 2) + r;
                    int t = m & (T_ - 1);
                    float sn, cs; __sincosf((float)t * invf[p], &sn, &cs);
                    float x1 = o[p][r], x2 = o[p + 2][r];
                    o[p][r]     =  x1 * cs + x2 * sn;
                    o[p + 2][r] = -x1 * sn + x2 * cs;
                }
            }
        }

#pragma unroll
        for (int r = 0; r < 4; ++r) {
            int m = m0 + wv * 32 + mf * 16 + ((lane >> 4) << 2) + r;
            int b = m >> 10, t = m & (T_ - 1);
            int bh = b * H_ + h;
            size_t base = ((size_t)bh * T_ + t) * HD_;
            float nrm = 0.f;
#pragma unroll
            for (int nf = 0; nf < 4; ++nf) {
                int d = nf * 16 + (lane & 15);
                float v = o[nf][r];
                nrm += v * v;
                ushort bv = f2bf(sector == 1 ? v * inv_k : v);
                if (sector == 0)      Qo[base + d] = bv;
                else if (sector == 1) Ko[base + d] = bv;
                else                  Vo[base + d] = bv;
            }
            if (sector < 2) {
#pragma unroll
                for (int mk = 1; mk < 16; mk <<= 1) nrm += __shfl_xor(nrm, mk);
                if ((lane & 15) == 0) {
                    float v0 = sqrtf(kc + nrm);
                    if (sector == 0) q0g[(size_t)bh * T_ + t] = v0;
                    else             k0g[(size_t)bh * T_ + t] = v0 * inv_k;
                }
            }
        }
    }
}

// ---------------------------------------------------------------------------
// Attention: paired q-tiles, fixed-max softmax. Ps[4] (r12-validated):
// per-wave buffer reused B-then-A; in-order per-wave LDS makes WAR safe.
// ---------------------------------------------------------------------------
__global__ __launch_bounds__(256, 2) void attn_fwd(
    const ushort* __restrict__ Q, const ushort* __restrict__ K, const ushort* __restrict__ V,
    const float* __restrict__ q0g, const float* __restrict__ k0g,
    const float* __restrict__ hyp, ushort* __restrict__ AO)
{
    __shared__ ushort Ks[64 * 64];
    __shared__ ushort Vts[64 * 64];
    __shared__ ushort Ps[4][16 * 64];
    __shared__ float k0s[64];

    const int tid = threadIdx.x, lane = tid & 63, wv = tid >> 6;
    const int pr = blockIdx.x >> 6;
    const int bh = blockIdx.x & 63;
    const int h = bh & (H_ - 1);
    const int qa = pr, qb = 15 - pr, nt = qb + 1;
    const float c3 = sqrtf(hyp[h]) * 0.48045301391820142f;  // sqrt(k)*ln2^2
    const float e3 = 6.931471805599453e-07f;                // 1e-6*ln2

    const ushort* Kb = K + (size_t)bh * T_ * HD_;
    const ushort* Vb = V + (size_t)bh * T_ * HD_;

    bf16x8 aqA[2], aqB[2];
    {
        const ushort* qA = Q + ((size_t)bh * T_ + qa * 64 + wv * 16 + (lane & 15)) * HD_;
        const ushort* qB = Q + ((size_t)bh * T_ + qb * 64 + wv * 16 + (lane & 15)) * HD_;
#pragma unroll
        for (int ks = 0; ks < 2; ++ks) {
            aqA[ks] = __builtin_bit_cast(bf16x8, *(const uint4*)(qA + ks * 32 + ((lane >> 4) << 3)));
            aqB[ks] = __builtin_bit_cast(bf16x8, *(const uint4*)(qB + ks * 32 + ((lane >> 4) << 3)));
        }
    }
    float q0A[4], q0B[4];
#pragma unroll
    for (int r = 0; r < 4; ++r) {
        int rr = wv * 16 + ((lane >> 4) << 2) + r;
        q0A[r] = q0g[(size_t)bh * T_ + qa * 64 + rr];
        q0B[r] = q0g[(size_t)bh * T_ + qb * 64 + rr];
    }

    f32x4 oaccA[4] = {}, oaccB[4] = {};
    float lpA[4] = {}, lpB[4] = {};

    const int krow = tid >> 3, koff = tid & 7;
    const int sp = tid >> 3, dc = tid & 7;
    uint4 kv0, kv1, vv0, vv1;
    float kz = 0.f;
    auto issue = [&](int s0) {
        kv0 = *(const uint4*)(Kb + (size_t)(s0 + krow) * HD_ + koff * 8);
        kv1 = *(const uint4*)(Kb + (size_t)(s0 + 32 + krow) * HD_ + koff * 8);
        vv0 = *(const uint4*)(Vb + (size_t)(s0 + 2 * sp) * HD_ + dc * 8);
        vv1 = *(const uint4*)(Vb + (size_t)(s0 + 2 * sp + 1) * HD_ + dc * 8);
        if (tid < 64) kz = k0g[(size_t)bh * T_ + s0 + tid];
    };

    auto geom = [&](const f32x4* sc, const float* q0, const float* k0r, float p[4][4]) {
#pragma unroll
        for (int r = 0; r < 4; ++r)
#pragma unroll
            for (int sf = 0; sf < 4; ++sf) {
                float arg = fmaf(q0[r], k0r[sf], -sc[sf][r]);
                arg = fmaxf(arg, 1.0f + 1e-6f);
                float t = fmaf(arg, arg, -1.0f);
                float u = arg + __builtin_amdgcn_sqrtf(t);
                float l2 = __builtin_amdgcn_logf(u);
                float w2 = fmaf(l2, c3, e3);
                float rv = fminf(__builtin_amdgcn_rcpf(w2), 30.0f);
                p[sf][r] = __builtin_amdgcn_exp2f(rv);
            }
    };
    auto mask_diag = [&](float p[4][4]) {
        const int qloc = wv * 16 + ((lane >> 4) << 2);
#pragma unroll
        for (int r = 0; r < 4; ++r)
#pragma unroll
            for (int sf = 0; sf < 4; ++sf)
                if (sf * 16 + (lane & 15) > qloc + r) p[sf][r] = 0.f;
    };
    auto pv_step = [&](float p[4][4], ushort* ps, const bf16x8 (&vf)[2][4],
                       f32x4* oacc, float* lp) {
#pragma unroll
        for (int r = 0; r < 4; ++r) {
            int row = ((lane >> 4) << 2) + r;
#pragma unroll
            for (int sf = 0; sf < 4; ++sf) {
                int addr = (row * 128 + (sf * 16 + (lane & 15)) * 2) ^ (((row >> 2) & 3) << 5);
                *(ushort*)((char*)ps + addr) = f2bf(p[sf][r]);
            }
            lp[r] += (p[0][r] + p[1][r]) + (p[2][r] + p[3][r]);
        }
#pragma unroll
        for (int ks = 0; ks < 2; ++ks) {
            bf16x8 ap = lds_frag_p(ps, lane & 15, ks * 64 + ((lane >> 4) << 4));
#pragma unroll
            for (int df = 0; df < 4; ++df)
                oacc[df] = mfma16(ap, vf[ks][df], oacc[df]);
        }
    };

    issue(0);

    for (int it = 0; it < nt; ++it) {
        const bool actA = (it <= qa);
        __syncthreads();
        {
            *(uint4*)((char*)Ks + ((tid * 16) ^ ((krow & 7) << 4))) = kv0;
            int c1 = tid + 256;
            *(uint4*)((char*)Ks + ((c1 * 16) ^ (((c1 >> 3) & 7) << 4))) = kv1;
            union { uint4 v; ushort u[8]; } a, b;
            a.v = vv0; b.v = vv1;
#pragma unroll
            for (int j = 0; j < 8; ++j) {
                int d = dc * 8 + j;
                uint pack = (uint)a.u[j] | ((uint)b.u[j] << 16);
                *(uint*)((char*)Vts + ((d * 128 + sp * 4) ^ (((j ^ dc) & 7) << 4))) = pack;
            }
            if (tid < 64) k0s[tid] = kz;
        }
        if (it + 1 < nt) issue((it + 1) * 64);
        __syncthreads();

        bf16x8 bk[2][4];
#pragma unroll
        for (int ks = 0; ks < 2; ++ks)
#pragma unroll
            for (int sf = 0; sf < 4; ++sf)
                bk[ks][sf] = lds_frag(Ks, sf * 16 + (lane & 15), ks * 64 + ((lane >> 4) << 4));

        float k0r[4];
#pragma unroll
        for (int sf = 0; sf < 4; ++sf) k0r[sf] = k0s[sf * 16 + (lane & 15)];

        f32x4 scB[4] = {};
#pragma unroll
        for (int ks = 0; ks < 2; ++ks)
#pragma unroll
            for (int sf = 0; sf < 4; ++sf)
                scB[sf] = mfma16(aqB[ks], bk[ks][sf], scB[sf]);
        f32x4 scA[4] = {};
        if (actA) {
#pragma unroll
            for (int ks = 0; ks < 2; ++ks)
#pragma unroll
                for (int sf = 0; sf < 4; ++sf)
                    scA[sf] = mfma16(aqA[ks], bk[ks][sf], scA[sf]);
        }

        bf16x8 vf[2][4];
#pragma unroll
        for (int ks = 0; ks < 2; ++ks)
#pragma unroll
            for (int df = 0; df < 4; ++df)
                vf[ks][df] = lds_frag_v(Vts, df * 16 + (lane & 15), ks * 64 + ((lane >> 4) << 4));

        float pB[4][4];
        geom(scB, q0B, k0r, pB);
        if (it == qb) mask_diag(pB);
        pv_step(pB, Ps[wv], vf, oaccB, lpB);

        if (actA) {
            float pA[4][4];
            geom(scA, q0A, k0r, pA);
            if (it == qa) mask_diag(pA);
            pv_step(pA, Ps[wv], vf, oaccA, lpA);
        }
    }

    const int b = bh >> 4;
    auto epi = [&](f32x4* oacc, float* lp, int qt) {
#pragma unroll
        for (int r = 0; r < 4; ++r) {
            float s = lp[r];
#pragma unroll
            for (int mk = 1; mk < 16; mk <<= 1) s += __shfl_xor(s, mk);
            float invl = __builtin_amdgcn_rcpf(s);
            int t = qt * 64 + wv * 16 + ((lane >> 4) << 2) + r;
            size_t base = ((size_t)b * T_ + t) * C_ + h * HD_;
#pragma unroll
            for (int df = 0; df < 4; ++df)
                AO[base + df * 16 + (lane & 15)] = f2bf(oacc[df][r] * invl);
        }
    };
    epi(oaccA, lpA, qa);
    epi(oaccB, lpB, qb);
}

// ---------------------------------------------------------------------------
// GEMM2: out = attn @ W_out^T -> fp32. Same dbuf single-barrier structure.
// ---------------------------------------------------------------------------
__global__ __launch_bounds__(256) void gemm_out(
    const ushort* __restrict__ Ab, const ushort* __restrict__ Wb, float* __restrict__ Out)
{
    __shared__ ushort As0[128 * 64], Bs0[64 * 64];
    __shared__ ushort As1[128 * 64], Bs1[64 * 64];
    const int tid = threadIdx.x, lane = tid & 63, wv = tid >> 6;
    const int m0 = blockIdx.x * 128, n0 = blockIdx.y * 64;
    const ushort* Asrc = Ab + (size_t)m0 * C_;
    const ushort* Bsrc = Wb + (size_t)n0 * C_;

    GEMM_DBUF_STAGING(Asrc, Bsrc);

    f32x4 acc[2][4] = {};
    GEMM_DBUF_LOOP();

#pragma unroll
    for (int mf = 0; mf < 2; ++mf)
#pragma unroll
        for (int r = 0; r < 4; ++r) {
            int m = m0 + wv * 32 + mf * 16 + ((lane >> 4) << 2) + r;
#pragma unroll
            for (int nf = 0; nf < 4; ++nf) {
                int n = n0 + nf * 16 + (lane & 15);
                Out[(size_t)m * C_ + n] = acc[mf][nf][r];
            }
        }
}

// ---------------------------------------------------------------------------
extern "C" void kernel_launch(void* const* d_in, const int* in_sizes, int n_in,
                              void* d_out, int out_size, void* d_ws, size_t ws_size,
                              hipStream_t stream)
{
    const float* x    = (const float*)d_in[0];
    const float* wqkv = (const float*)d_in[1];
    const float* wout = (const float*)d_in[2];
    const float* hyp  = (const float*)d_in[3];

    char* ws = (char*)d_ws;
    ushort* xb    = (ushort*)(ws + 0);
    ushort* wqkvb = (ushort*)(ws + 8388608);
    ushort* woutb = (ushort*)(ws + 14680064);
    ushort* Qb    = (ushort*)(ws + 16777216);
    ushort* Kb    = (ushort*)(ws + 25165824);
    ushort* Vb    = (ushort*)(ws + 33554432);
    ushort* Ab    = (ushort*)(ws + 41943040);
    float*  q0    = (float*)(ws + 50331648);
    float*  k0    = (float*)(ws + 50593792);

    cast_all<<<8192, 256, 0, stream>>>(x, wqkv, wout, xb, wqkvb, woutb);

    gemm_qkv<<<dim3(32, 48), 256, 0, stream>>>(xb, wqkvb, hyp, Qb, Kb, Vb, q0, k0);
    attn_fwd<<<512, 256, 0, stream>>>(Qb, Kb, Vb, q0, k0, hyp, Ab);
    gemm_out<<<dim3(32, 16), 256, 0, stream>>>(Ab, woutb, (float*)d_out);
}

// Round 15
// 93.741 us; speedup vs baseline: 1.2674x; 1.0188x over previous
//
#include <hip/hip_runtime.h>

#define B_ 4
#define T_ 1024
#define C_ 1024
#define H_ 16
#define HD_ 64

typedef short bf16x8 __attribute__((ext_vector_type(8)));
typedef float f32x4 __attribute__((ext_vector_type(4)));

__device__ __forceinline__ ushort f2bf(float f) {
    union { float f; unsigned u; } v; v.f = f;
    unsigned u = v.u;
    unsigned r = (u + 0x7fffu + ((u >> 16) & 1u)) >> 16;
    return (ushort)r;
}

__device__ __forceinline__ f32x4 mfma16(bf16x8 a, bf16x8 b, f32x4 c) {
    return __builtin_amdgcn_mfma_f32_16x16x32_bf16(a, b, c, 0, 0, 0);
}

// [rows][64] ushort tile, swizzle byte ^= (row&7)<<4 (K/A/B tiles).
__device__ __forceinline__ bf16x8 lds_frag(const ushort* base, int row, int byteoff) {
    int addr = (row * 128 + byteoff) ^ ((row & 7) << 4);
    uint4 u = *(const uint4*)((const char*)base + addr);
    return __builtin_bit_cast(bf16x8, u);
}

// V^T tile: byte ^= (((d&7)^(d>>3))&7)<<4.
__device__ __forceinline__ bf16x8 lds_frag_v(const ushort* base, int d, int byteoff) {
    int addr = (d * 128 + byteoff) ^ ((((d & 7) ^ (d >> 3)) & 7) << 4);
    uint4 u = *(const uint4*)((const char*)base + addr);
    return __builtin_bit_cast(bf16x8, u);
}

// P tile (16 rows): swizzle ((row>>2)&3)<<5.
__device__ __forceinline__ bf16x8 lds_frag_p(const ushort* base, int row, int byteoff) {
    int addr = (row * 128 + byteoff) ^ (((row >> 2) & 3) << 5);
    uint4 u = *(const uint4*)((const char*)base + addr);
    return __builtin_bit_cast(bf16x8, u);
}

// Raw barrier: lgkmcnt(0) for LDS-write visibility, no vmcnt drain.
__device__ __forceinline__ void bar_lds() {
    asm volatile("s_waitcnt lgkmcnt(0)" ::: "memory");
    __builtin_amdgcn_sched_barrier(0);
    __builtin_amdgcn_s_barrier();
    __builtin_amdgcn_sched_barrier(0);
}

// One fused cast kernel for all three fp32->bf16 conversions.
__global__ void cast_all(const float* __restrict__ x, const float* __restrict__ wqkv,
                         const float* __restrict__ wout,
                         ushort* __restrict__ xb, ushort* __restrict__ wqkvb,
                         ushort* __restrict__ woutb) {
    int i = (blockIdx.x * 256 + threadIdx.x) * 4;
    const float* src; ushort* dst; int off;
    if (i < 4194304)      { src = x;    dst = xb;    off = i; }
    else if (i < 7340032) { src = wqkv; dst = wqkvb; off = i - 4194304; }
    else                  { src = wout; dst = woutb; off = i - 7340032; }
    float4 v = *(const float4*)(src + off);
    ushort4 o = make_ushort4(f2bf(v.x), f2bf(v.y), f2bf(v.z), f2bf(v.w));
    *(ushort4*)(dst + off) = o;
}

// ---------------------------------------------------------------------------
// ROUND 15 THEORY: five schedules at 128x64 all hit ~51us because the LDS
// port is the floor there (72 b128 instrs/CU-iter ~= 864cy x 96 iters = 35us).
// The 128x128 / 2x2-wave tile HALVES LDS instrs per MFMA (8 reads : 16 MFMA).
// r10 tried that tile and died of 2-barrier serialization at 3 blocks/CU;
// r14's dbuf+raw-barrier removes exactly that. This round composes them.
// ---------------------------------------------------------------------------

// ---- 128x64 pieces (gemm_out keeps r14's proven config) -------------------
#define GEMM_COMPUTE_128x64(As, Bs)                                                       \
    {                                                                                     \
        _Pragma("unroll")                                                                 \
        for (int ks = 0; ks < 2; ++ks) {                                                  \
            bf16x8 af[2], bfr[4];                                                         \
            _Pragma("unroll")                                                             \
            for (int mf = 0; mf < 2; ++mf)                                                \
                af[mf] = lds_frag(As, wv * 32 + mf * 16 + (lane & 15),                    \
                                  ks * 64 + ((lane >> 4) << 4));                          \
            _Pragma("unroll")                                                             \
            for (int nf = 0; nf < 4; ++nf)                                                \
                bfr[nf] = lds_frag(Bs, nf * 16 + (lane & 15),                             \
                                   ks * 64 + ((lane >> 4) << 4));                         \
            _Pragma("unroll")                                                             \
            for (int mf = 0; mf < 2; ++mf)                                                \
                _Pragma("unroll")                                                         \
                for (int nf = 0; nf < 4; ++nf)                                            \
                    acc[mf][nf] = mfma16(af[mf], bfr[nf], acc[mf][nf]);                   \
        }                                                                                 \
    }

#define GEMM_DBUF_STAGING(Asrc, Bsrc)                                                     \
    const int srow = tid >> 3, soff = (tid & 7) * 8;                                      \
    const int swz = (srow & 7) << 4;                                                      \
    uint4 a0, a1, a2, a3, b0, b1;                                                         \
    auto issue = [&](int kt) {                                                            \
        const ushort* Ap = Asrc + kt * 64;                                                \
        const ushort* Bp = Bsrc + kt * 64;                                                \
        a0 = *(const uint4*)(Ap + (size_t)srow * C_ + soff);                              \
        a1 = *(const uint4*)(Ap + (size_t)(32 + srow) * C_ + soff);                       \
        a2 = *(const uint4*)(Ap + (size_t)(64 + srow) * C_ + soff);                       \
        a3 = *(const uint4*)(Ap + (size_t)(96 + srow) * C_ + soff);                       \
        b0 = *(const uint4*)(Bp + (size_t)srow * C_ + soff);                              \
        b1 = *(const uint4*)(Bp + (size_t)(32 + srow) * C_ + soff);                       \
    };                                                                                    \
    auto lwrite = [&](ushort* Ad, ushort* Bd) {                                           \
        *(uint4*)((char*)Ad + ((tid * 16) ^ swz)) = a0;                                   \
        *(uint4*)((char*)Ad + (((tid + 256) * 16) ^ swz)) = a1;                           \
        *(uint4*)((char*)Ad + (((tid + 512) * 16) ^ swz)) = a2;                           \
        *(uint4*)((char*)Ad + (((tid + 768) * 16) ^ swz)) = a3;                           \
        *(uint4*)((char*)Bd + ((tid * 16) ^ swz)) = b0;                                   \
        *(uint4*)((char*)Bd + (((tid + 256) * 16) ^ swz)) = b1;                           \
    }

#define GEMM_DBUF_LOOP(COMPUTE)                                                           \
    issue(0);                                                                             \
    lwrite(As0, Bs0);                                                                     \
    issue(1);                                                                             \
    bar_lds();                                                                            \
    for (int kt = 0; kt < 12; kt += 2) {                                                  \
        lwrite(As1, Bs1);                                                                 \
        issue(kt + 2);                                                                    \
        COMPUTE(As0, Bs0);                                                                \
        bar_lds();                                                                        \
        lwrite(As0, Bs0);                                                                 \
        issue(kt + 3);                                                                    \
        COMPUTE(As1, Bs1);                                                                \
        bar_lds();                                                                        \
    }                                                                                     \
    lwrite(As1, Bs1);                                                                     \
    issue(14);                                                                            \
    COMPUTE(As0, Bs0);                                                                    \
    bar_lds();                                                                            \
    lwrite(As0, Bs0);                                                                     \
    issue(15);                                                                            \
    COMPUTE(As1, Bs1);                                                                    \
    bar_lds();                                                                            \
    lwrite(As1, Bs1);                                                                     \
    COMPUTE(As0, Bs0);                                                                    \
    bar_lds();                                                                            \
    COMPUTE(As1, Bs1);

// ---- 128x128 pieces (gemm_qkv) --------------------------------------------
#define GEMM_COMPUTE_128x128(As, Bs)                                                      \
    {                                                                                     \
        _Pragma("unroll")                                                                 \
        for (int ks = 0; ks < 2; ++ks) {                                                  \
            bf16x8 af[4], bfr[4];                                                         \
            _Pragma("unroll")                                                             \
            for (int mf = 0; mf < 4; ++mf)                                                \
                af[mf] = lds_frag(As, wr * 64 + mf * 16 + (lane & 15),                    \
                                  ks * 64 + ((lane >> 4) << 4));                          \
            _Pragma("unroll")                                                             \
            for (int nf = 0; nf < 4; ++nf)                                                \
                bfr[nf] = lds_frag(Bs, wc * 64 + nf * 16 + (lane & 15),                   \
                                   ks * 64 + ((lane >> 4) << 4));                         \
            _Pragma("unroll")                                                             \
            for (int mf = 0; mf < 4; ++mf)                                                \
                _Pragma("unroll")                                                         \
                for (int nf = 0; nf < 4; ++nf)                                            \
                    acc[mf][nf] = mfma16(af[mf], bfr[nf], acc[mf][nf]);                   \
        }                                                                                 \
    }

#define GEMM_DBUF_STAGING2(Asrc, Bsrc)                                                    \
    const int srow = tid >> 3, soff = (tid & 7) * 8;                                      \
    const int swz = (srow & 7) << 4;                                                      \
    uint4 a0, a1, a2, a3, b0, b1, b2, b3;                                                 \
    auto issue = [&](int kt) {                                                            \
        const ushort* Ap = Asrc + kt * 64;                                                \
        const ushort* Bp = Bsrc + kt * 64;                                                \
        a0 = *(const uint4*)(Ap + (size_t)srow * C_ + soff);                              \
        a1 = *(const uint4*)(Ap + (size_t)(32 + srow) * C_ + soff);                       \
        a2 = *(const uint4*)(Ap + (size_t)(64 + srow) * C_ + soff);                       \
        a3 = *(const uint4*)(Ap + (size_t)(96 + srow) * C_ + soff);                       \
        b0 = *(const uint4*)(Bp + (size_t)srow * C_ + soff);                              \
        b1 = *(const uint4*)(Bp + (size_t)(32 + srow) * C_ + soff);                       \
        b2 = *(const uint4*)(Bp + (size_t)(64 + srow) * C_ + soff);                       \
        b3 = *(const uint4*)(Bp + (size_t)(96 + srow) * C_ + soff);                       \
    };                                                                                    \
    auto lwrite = [&](ushort* Ad, ushort* Bd) {                                           \
        *(uint4*)((char*)Ad + ((tid * 16) ^ swz)) = a0;                                   \
        *(uint4*)((char*)Ad + (((tid + 256) * 16) ^ swz)) = a1;                           \
        *(uint4*)((char*)Ad + (((tid + 512) * 16) ^ swz)) = a2;                           \
        *(uint4*)((char*)Ad + (((tid + 768) * 16) ^ swz)) = a3;                           \
        *(uint4*)((char*)Bd + ((tid * 16) ^ swz)) = b0;                                   \
        *(uint4*)((char*)Bd + (((tid + 256) * 16) ^ swz)) = b1;                           \
        *(uint4*)((char*)Bd + (((tid + 512) * 16) ^ swz)) = b2;                           \
        *(uint4*)((char*)Bd + (((tid + 768) * 16) ^ swz)) = b3;                           \
    }

// ---------------------------------------------------------------------------
// GEMM1: qkv = x @ W_qkv^T, fused RoPE + norms + kappa-prescale.
// 128x128 tile, 2x2 waves, dbuf + 1 raw barrier/K-iter. Grid (32 m, 24 n).
// ---------------------------------------------------------------------------
__global__ __launch_bounds__(256) void gemm_qkv(
    const ushort* __restrict__ Xb, const ushort* __restrict__ Wb,
    const float* __restrict__ hyp,
    ushort* __restrict__ Qo, ushort* __restrict__ Ko, ushort* __restrict__ Vo,
    float* __restrict__ q0g, float* __restrict__ k0g)
{
    __shared__ ushort As0[128 * 64], Bs0[128 * 64];
    __shared__ ushort As1[128 * 64], Bs1[128 * 64];
    const int tid = threadIdx.x, lane = tid & 63, wv = tid >> 6;
    const int wr = wv >> 1, wc = wv & 1;
    const int m0 = blockIdx.x * 128, n0 = blockIdx.y * 128;
    const ushort* Asrc = Xb + (size_t)m0 * C_;
    const ushort* Bsrc = Wb + (size_t)n0 * C_;

    GEMM_DBUF_STAGING2(Asrc, Bsrc);

    f32x4 acc[4][4] = {};
    GEMM_DBUF_LOOP(GEMM_COMPUTE_128x128);

    // epilogue (r10-verified 2x2 version) ------------------------------------
    const int sector = n0 >> 10;            // 0=q 1=k 2=v
    const int h = ((n0 & 1023) >> 6) + wc;
    const float kc = hyp[h];
    const float inv_k = 1.0f / kc;
    float invf[2];
    invf[0] = __expf(-0.28782313662425572f * (float)(lane & 15));        // 10000^(-j/32)
    invf[1] = __expf(-0.28782313662425572f * (float)(16 + (lane & 15)));

#pragma unroll
    for (int mf = 0; mf < 4; ++mf) {
        float o[4][4];
#pragma unroll
        for (int nf = 0; nf < 4; ++nf)
#pragma unroll
            for (int r = 0; r < 4; ++r) o[nf][r] = acc[mf][nf][r];

        if (sector < 2) {
#pragma unroll
            for (int p = 0; p < 2; ++p) {
#pragma unroll
                for (int r = 0; r < 4; ++r) {
                    int m = m0 + wr * 64 + mf * 16 + ((lane >> 4) << 2) + r;
                    int t = m & (T_ - 1);
                    float sn, cs; __sincosf((float)t * invf[p], &sn, &cs);
                    float x1 = o[p][r], x2 = o[p + 2][r];
                    o[p][r]     =  x1 * cs + x2 * sn;
                    o[p + 2][r] = -x1 * sn + x2 * cs;
                }
            }
        }

#pragma unroll
        for (int r = 0; r < 4; ++r) {
            int m = m0 + wr * 64 + mf * 16 + ((lane >> 4) << 2) + r;
            int b = m >> 10, t = m & (T_ - 1);
            int bh = b * H_ + h;
            size_t base = ((size_t)bh * T_ + t) * HD_;
            float nrm = 0.f;
#pragma unroll
            for (int nf = 0; nf < 4; ++nf) {
                int d = nf * 16 + (lane & 15);
                float v = o[nf][r];
                nrm += v * v;
                ushort bv = f2bf(sector == 1 ? v * inv_k : v);
                if (sector == 0)      Qo[base + d] = bv;
                else if (sector == 1) Ko[base + d] = bv;
                else                  Vo[base + d] = bv;
            }
            if (sector < 2) {
#pragma unroll
                for (int mk = 1; mk < 16; mk <<= 1) nrm += __shfl_xor(nrm, mk);
                if ((lane & 15) == 0) {
                    float v0 = sqrtf(kc + nrm);
                    if (sector == 0) q0g[(size_t)bh * T_ + t] = v0;
                    else             k0g[(size_t)bh * T_ + t] = v0 * inv_k;
                }
            }
        }
    }
}

// ---------------------------------------------------------------------------
// Attention (r14 exact, proven): paired q-tiles, fixed-max softmax, Ps[4].
// ---------------------------------------------------------------------------
__global__ __launch_bounds__(256, 2) void attn_fwd(
    const ushort* __restrict__ Q, const ushort* __restrict__ K, const ushort* __restrict__ V,
    const float* __restrict__ q0g, const float* __restrict__ k0g,
    const float* __restrict__ hyp, ushort* __restrict__ AO)
{
    __shared__ ushort Ks[64 * 64];
    __shared__ ushort Vts[64 * 64];
    __shared__ ushort Ps[4][16 * 64];
    __shared__ float k0s[64];

    const int tid = threadIdx.x, lane = tid & 63, wv = tid >> 6;
    const int pr = blockIdx.x >> 6;
    const int bh = blockIdx.x & 63;
    const int h = bh & (H_ - 1);
    const int qa = pr, qb = 15 - pr, nt = qb + 1;
    const float c3 = sqrtf(hyp[h]) * 0.48045301391820142f;  // sqrt(k)*ln2^2
    const float e3 = 6.931471805599453e-07f;                // 1e-6*ln2

    const ushort* Kb = K + (size_t)bh * T_ * HD_;
    const ushort* Vb = V + (size_t)bh * T_ * HD_;

    bf16x8 aqA[2], aqB[2];
    {
        const ushort* qA = Q + ((size_t)bh * T_ + qa * 64 + wv * 16 + (lane & 15)) * HD_;
        const ushort* qB = Q + ((size_t)bh * T_ + qb * 64 + wv * 16 + (lane & 15)) * HD_;
#pragma unroll
        for (int ks = 0; ks < 2; ++ks) {
            aqA[ks] = __builtin_bit_cast(bf16x8, *(const uint4*)(qA + ks * 32 + ((lane >> 4) << 3)));
            aqB[ks] = __builtin_bit_cast(bf16x8, *(const uint4*)(qB + ks * 32 + ((lane >> 4) << 3)));
        }
    }
    float q0A[4], q0B[4];
#pragma unroll
    for (int r = 0; r < 4; ++r) {
        int rr = wv * 16 + ((lane >> 4) << 2) + r;
        q0A[r] = q0g[(size_t)bh * T_ + qa * 64 + rr];
        q0B[r] = q0g[(size_t)bh * T_ + qb * 64 + rr];
    }

    f32x4 oaccA[4] = {}, oaccB[4] = {};
    float lpA[4] = {}, lpB[4] = {};

    const int krow = tid >> 3, koff = tid & 7;
    const int sp = tid >> 3, dc = tid & 7;
    uint4 kv0, kv1, vv0, vv1;
    float kz = 0.f;
    auto issue = [&](int s0) {
        kv0 = *(const uint4*)(Kb + (size_t)(s0 + krow) * HD_ + koff * 8);
        kv1 = *(const uint4*)(Kb + (size_t)(s0 + 32 + krow) * HD_ + koff * 8);
        vv0 = *(const uint4*)(Vb + (size_t)(s0 + 2 * sp) * HD_ + dc * 8);
        vv1 = *(const uint4*)(Vb + (size_t)(s0 + 2 * sp + 1) * HD_ + dc * 8);
        if (tid < 64) kz = k0g[(size_t)bh * T_ + s0 + tid];
    };

    auto geom = [&](const f32x4* sc, const float* q0, const float* k0r, float p[4][4]) {
#pragma unroll
        for (int r = 0; r < 4; ++r)
#pragma unroll
            for (int sf = 0; sf < 4; ++sf) {
                float arg = fmaf(q0[r], k0r[sf], -sc[sf][r]);
                arg = fmaxf(arg, 1.0f + 1e-6f);
                float t = fmaf(arg, arg, -1.0f);
                float u = arg + __builtin_amdgcn_sqrtf(t);
                float l2 = __builtin_amdgcn_logf(u);
                float w2 = fmaf(l2, c3, e3);
                float rv = fminf(__builtin_amdgcn_rcpf(w2), 30.0f);
                p[sf][r] = __builtin_amdgcn_exp2f(rv);
            }
    };
    auto mask_diag = [&](float p[4][4]) {
        const int qloc = wv * 16 + ((lane >> 4) << 2);
#pragma unroll
        for (int r = 0; r < 4; ++r)
#pragma unroll
            for (int sf = 0; sf < 4; ++sf)
                if (sf * 16 + (lane & 15) > qloc + r) p[sf][r] = 0.f;
    };
    auto pv_step = [&](float p[4][4], ushort* ps, const bf16x8 (&vf)[2][4],
                       f32x4* oacc, float* lp) {
#pragma unroll
        for (int r = 0; r < 4; ++r) {
            int row = ((lane >> 4) << 2) + r;
#pragma unroll
            for (int sf = 0; sf < 4; ++sf) {
                int addr = (row * 128 + (sf * 16 + (lane & 15)) * 2) ^ (((row >> 2) & 3) << 5);
                *(ushort*)((char*)ps + addr) = f2bf(p[sf][r]);
            }
            lp[r] += (p[0][r] + p[1][r]) + (p[2][r] + p[3][r]);
        }
#pragma unroll
        for (int ks = 0; ks < 2; ++ks) {
            bf16x8 ap = lds_frag_p(ps, lane & 15, ks * 64 + ((lane >> 4) << 4));
#pragma unroll
            for (int df = 0; df < 4; ++df)
                oacc[df] = mfma16(ap, vf[ks][df], oacc[df]);
        }
    };

    issue(0);

    for (int it = 0; it < nt; ++it) {
        const bool actA = (it <= qa);
        __syncthreads();
        {
            *(uint4*)((char*)Ks + ((tid * 16) ^ ((krow & 7) << 4))) = kv0;
            int c1 = tid + 256;
            *(uint4*)((char*)Ks + ((c1 * 16) ^ (((c1 >> 3) & 7) << 4))) = kv1;
            union { uint4 v; ushort u[8]; } a, b;
            a.v = vv0; b.v = vv1;
#pragma unroll
            for (int j = 0; j < 8; ++j) {
                int d = dc * 8 + j;
                uint pack = (uint)a.u[j] | ((uint)b.u[j] << 16);
                *(uint*)((char*)Vts + ((d * 128 + sp * 4) ^ (((j ^ dc) & 7) << 4))) = pack;
            }
            if (tid < 64) k0s[tid] = kz;
        }
        if (it + 1 < nt) issue((it + 1) * 64);
        __syncthreads();

        bf16x8 bk[2][4];
#pragma unroll
        for (int ks = 0; ks < 2; ++ks)
#pragma unroll
            for (int sf = 0; sf < 4; ++sf)
                bk[ks][sf] = lds_frag(Ks, sf * 16 + (lane & 15), ks * 64 + ((lane >> 4) << 4));

        float k0r[4];
#pragma unroll
        for (int sf = 0; sf < 4; ++sf) k0r[sf] = k0s[sf * 16 + (lane & 15)];

        f32x4 scB[4] = {};
#pragma unroll
        for (int ks = 0; ks < 2; ++ks)
#pragma unroll
            for (int sf = 0; sf < 4; ++sf)
                scB[sf] = mfma16(aqB[ks], bk[ks][sf], scB[sf]);
        f32x4 scA[4] = {};
        if (actA) {
#pragma unroll
            for (int ks = 0; ks < 2; ++ks)
#pragma unroll
                for (int sf = 0; sf < 4; ++sf)
                    scA[sf] = mfma16(aqA[ks], bk[ks][sf], scA[sf]);
        }

        bf16x8 vf[2][4];
#pragma unroll
        for (int ks = 0; ks < 2; ++ks)
#pragma unroll
            for (int df = 0; df < 4; ++df)
                vf[ks][df] = lds_frag_v(Vts, df * 16 + (lane & 15), ks * 64 + ((lane >> 4) << 4));

        float pB[4][4];
        geom(scB, q0B, k0r, pB);
        if (it == qb) mask_diag(pB);
        pv_step(pB, Ps[wv], vf, oaccB, lpB);

        if (actA) {
            float pA[4][4];
            geom(scA, q0A, k0r, pA);
            if (it == qa) mask_diag(pA);
            pv_step(pA, Ps[wv], vf, oaccA, lpA);
        }
    }

    const int b = bh >> 4;
    auto epi = [&](f32x4* oacc, float* lp, int qt) {
#pragma unroll
        for (int r = 0; r < 4; ++r) {
            float s = lp[r];
#pragma unroll
            for (int mk = 1; mk < 16; mk <<= 1) s += __shfl_xor(s, mk);
            float invl = __builtin_amdgcn_rcpf(s);
            int t = qt * 64 + wv * 16 + ((lane >> 4) << 2) + r;
            size_t base = ((size_t)b * T_ + t) * C_ + h * HD_;
#pragma unroll
            for (int df = 0; df < 4; ++df)
                AO[base + df * 16 + (lane & 15)] = f2bf(oacc[df][r] * invl);
        }
    };
    epi(oaccA, lpA, qa);
    epi(oaccB, lpB, qb);
}

// ---------------------------------------------------------------------------
// GEMM2: out = attn @ W_out^T -> fp32. r14's 128x64 dbuf structure (grid too
// small for 128^2).
// ---------------------------------------------------------------------------
__global__ __launch_bounds__(256) void gemm_out(
    const ushort* __restrict__ Ab, const ushort* __restrict__ Wb, float* __restrict__ Out)
{
    __shared__ ushort As0[128 * 64], Bs0[64 * 64];
    __shared__ ushort As1[128 * 64], Bs1[64 * 64];
    const int tid = threadIdx.x, lane = tid & 63, wv = tid >> 6;
    const int m0 = blockIdx.x * 128, n0 = blockIdx.y * 64;
    const ushort* Asrc = Ab + (size_t)m0 * C_;
    const ushort* Bsrc = Wb + (size_t)n0 * C_;

    GEMM_DBUF_STAGING(Asrc, Bsrc);

    f32x4 acc[2][4] = {};
    GEMM_DBUF_LOOP(GEMM_COMPUTE_128x64);

#pragma unroll
    for (int mf = 0; mf < 2; ++mf)
#pragma unroll
        for (int r = 0; r < 4; ++r) {
            int m = m0 + wv * 32 + mf * 16 + ((lane >> 4) << 2) + r;
#pragma unroll
            for (int nf = 0; nf < 4; ++nf) {
                int n = n0 + nf * 16 + (lane & 15);
                Out[(size_t)m * C_ + n] = acc[mf][nf][r];
            }
        }
}

// ---------------------------------------------------------------------------
extern "C" void kernel_launch(void* const* d_in, const int* in_sizes, int n_in,
                              void* d_out, int out_size, void* d_ws, size_t ws_size,
                              hipStream_t stream)
{
    const float* x    = (const float*)d_in[0];
    const float* wqkv = (const float*)d_in[1];
    const float* wout = (const float*)d_in[2];
    const float* hyp  = (const float*)d_in[3];

    char* ws = (char*)d_ws;
    ushort* xb    = (ushort*)(ws + 0);
    ushort* wqkvb = (ushort*)(ws + 8388608);
    ushort* woutb = (ushort*)(ws + 14680064);
    ushort* Qb    = (ushort*)(ws + 16777216);
    ushort* Kb    = (ushort*)(ws + 25165824);
    ushort* Vb    = (ushort*)(ws + 33554432);
    ushort* Ab    = (ushort*)(ws + 41943040);
    float*  q0    = (float*)(ws + 50331648);
    float*  k0    = (float*)(ws + 50593792);

    cast_all<<<8192, 256, 0, stream>>>(x, wqkv, wout, xb, wqkvb, woutb);

    gemm_qkv<<<dim3(32, 24), 256, 0, stream>>>(xb, wqkvb, hyp, Qb, Kb, Vb, q0, k0);
    attn_fwd<<<512, 256, 0, stream>>>(Qb, Kb, Vb, q0, k0, hyp, Ab);
    gemm_out<<<dim3(32, 16), 256, 0, stream>>>(Ab, woutb, (float*)d_out);
}